// Round 1
// baseline (201.287 us; speedup 1.0000x reference)
//
#include <hip/hip_runtime.h>
#include <cmath>

#define N_NODES 1500
#define NE 48000
#define ETOT (NE + N_NODES)   // 49500
#define IN_DIM 128
#define OUT_DIM 32
#define HEADS 4
#define HC 128                // HEADS*OUT
#define EDIM 16

// ---------------- init: zero accumulators (ws is poisoned 0xAA each call) ---
__global__ void k_init(int* deg, int* fillc, float* sumattr) {
    int gid = blockIdx.x * blockDim.x + threadIdx.x;
    if (gid < N_NODES) { deg[gid] = 0; fillc[gid] = 0; }
    if (gid < N_NODES * EDIM) sumattr[gid] = 0.f;
}

// ---------------- degree + incoming-edge-attr sums (for self-loop 'mean') ---
__global__ void k_deg_attr(const int* __restrict__ dst, const float* __restrict__ ef,
                           int* deg, float* sumattr) {
    int gid = blockIdx.x * blockDim.x + threadIdx.x;
    if (gid >= NE * EDIM) return;
    int e = gid >> 4, k = gid & 15;
    int d = dst[e];
    atomicAdd(&sumattr[d * EDIM + k], ef[gid]);
    if (k == 0) atomicAdd(&deg[d], 1);
}

// ---------------- exclusive scan of (deg+1) -> CSR offsets, single block ----
__global__ void k_scan(const int* __restrict__ deg, int* __restrict__ off) {
    __shared__ int part[512];
    int t = threadIdx.x;
    int base = t * 3;
    int d0 = (base     < N_NODES) ? deg[base] + 1     : 0;
    int d1 = (base + 1 < N_NODES) ? deg[base + 1] + 1 : 0;
    int d2 = (base + 2 < N_NODES) ? deg[base + 2] + 1 : 0;
    int sum = d0 + d1 + d2;
    part[t] = sum;
    __syncthreads();
    for (int o = 1; o < 512; o <<= 1) {
        int v = (t >= o) ? part[t - o] : 0;
        __syncthreads();
        part[t] += v;
        __syncthreads();
    }
    int excl = part[t] - sum;
    if (base     <= N_NODES) off[base]     = excl;
    if (base + 1 <= N_NODES) off[base + 1] = excl + d0;
    if (base + 2 <= N_NODES) off[base + 2] = excl + d0 + d1;
}

// ---------------- scatter edges (incl. self-loops) into CSR by dst ----------
__global__ void k_scatter(const int* __restrict__ src, const int* __restrict__ dst,
                          const int* __restrict__ off, int* fillc,
                          int* __restrict__ csr_src, int* __restrict__ csr_eid) {
    int e = blockIdx.x * blockDim.x + threadIdx.x;
    if (e >= ETOT) return;
    int s, d;
    if (e < NE) { s = src[e]; d = dst[e]; } else { s = d = e - NE; }
    int pos = atomicAdd(&fillc[d], 1);
    int idx = off[d] + pos;
    csr_src[idx] = s;
    csr_eid[idx] = e;
}

// ---------------- extra[e,h] = ea[e,:] @ P[:,h],  P = We contracted w/ att_e
__global__ void k_extra(const float* __restrict__ ef, const float* __restrict__ We,
                        const float* __restrict__ att_e, const float* __restrict__ sumattr,
                        const int* __restrict__ deg, float* __restrict__ extra) {
    __shared__ float P[EDIM * HEADS];
    int t = threadIdx.x;
    if (t < EDIM * HEADS) {
        int k = t >> 2, hh = t & 3;
        float a = 0.f;
        #pragma unroll
        for (int c = 0; c < OUT_DIM; ++c)
            a = fmaf(We[k * HC + hh * OUT_DIM + c], att_e[hh * OUT_DIM + c], a);
        P[t] = a;   // P[k*4+hh]
    }
    __syncthreads();
    int gid = blockIdx.x * blockDim.x + t;
    if (gid >= ETOT * HEADS) return;
    int e = gid >> 2, hh = gid & 3;
    float a = 0.f;
    if (e < NE) {
        #pragma unroll
        for (int k = 0; k < EDIM; ++k) a = fmaf(ef[e * EDIM + k], P[k * 4 + hh], a);
    } else {
        int i = e - NE;
        float inv = 1.0f / fmaxf((float)deg[i], 1.0f);
        #pragma unroll
        for (int k = 0; k < EDIM; ++k) a = fmaf(sumattr[i * EDIM + k] * inv, P[k * 4 + hh], a);
    }
    extra[gid] = a;
}

// ---------------- h = xin @ W (block/node, thread/out-col) + head dots ------
template <int IND>
__global__ void k_proj(const float* __restrict__ xin, const float* __restrict__ W,
                       const float* __restrict__ a_src, const float* __restrict__ a_dst,
                       float* __restrict__ h, float* __restrict__ asrc, float* __restrict__ adst) {
    __shared__ float xs[IND];
    int i = blockIdx.x, t = threadIdx.x;
    if (t < IND) xs[t] = xin[i * IND + t];
    __syncthreads();
    float acc = 0.f;
    #pragma unroll
    for (int k = 0; k < IND; ++k) acc = fmaf(xs[k], W[k * HC + t], acc);
    h[i * HC + t] = acc;
    float ps = acc * a_src[t];
    float pd = acc * a_dst[t];
    #pragma unroll
    for (int o = 16; o >= 1; o >>= 1) {
        ps += __shfl_down(ps, o, 32);
        pd += __shfl_down(pd, o, 32);
    }
    if ((t & 31) == 0) {
        asrc[i * HEADS + (t >> 5)] = ps;
        adst[i * HEADS + (t >> 5)] = pd;
    }
}

// ---------------- GAT aggregate: online softmax over incoming edges ---------
__global__ void k_gat(const float* __restrict__ h, const float* __restrict__ asrc,
                      const float* __restrict__ adst, const float* __restrict__ extra,
                      const int* __restrict__ off, const int* __restrict__ csr_src,
                      const int* __restrict__ csr_eid, const float* __restrict__ bias,
                      float* __restrict__ xout) {
    int i = blockIdx.x, t = threadIdx.x;
    int hh = t >> 5;
    float adst_i = adst[i * HEADS + hh];
    int beg = off[i], end = off[i + 1];
    float m = -INFINITY, s = 0.f, acc = 0.f;
    for (int j = beg; j < end; ++j) {
        int sn = csr_src[j];
        float alpha = asrc[sn * HEADS + hh] + adst_i;
        if (extra) alpha += extra[csr_eid[j] * HEADS + hh];
        alpha = alpha > 0.f ? alpha : 0.2f * alpha;   // leaky_relu(0.2)
        float mn = fmaxf(m, alpha);
        float r = __expf(m - mn);       // exp(-inf)=0 on first iter
        float w = __expf(alpha - mn);
        s = s * r + w;
        acc = acc * r + w * h[sn * HC + t];
        m = mn;
    }
    __shared__ float red[HC];
    red[t] = acc / s;                   // every node has a self loop -> s > 0
    __syncthreads();
    if (t < OUT_DIM)
        xout[i * OUT_DIM + t] =
            0.25f * (red[t] + red[t + 32] + red[t + 64] + red[t + 96]) + bias[t];
}

// ---------------- constant row value for x_edges rows >= E ------------------
__global__ void k_const(const float* __restrict__ fc1b, const float* __restrict__ fc2w,
                        const float* __restrict__ fc2b, float* __restrict__ c2) {
    if (threadIdx.x == 0) {
        float l0 = fc2b[0], l1 = fc2b[1];
        for (int j = 0; j < 32; ++j) {
            float a = fmaxf(fc1b[j], 0.f);
            l0 = fmaf(a, fc2w[2 * j], l0);
            l1 = fmaf(a, fc2w[2 * j + 1], l1);
        }
        float mx = fmaxf(l0, l1);
        float e0 = __expf(l0 - mx), e1 = __expf(l1 - mx);
        float inv = 1.f / (e0 + e1);
        c2[0] = e0 * inv;
        c2[1] = e1 * inv;
    }
}

// ---------------- broadcast-fill rows [E, n*n) with the constant ------------
__global__ void k_fill(const float* __restrict__ c2, float* __restrict__ out) {
    int gid = blockIdx.x * blockDim.x + threadIdx.x;
    const int nfl4 = ((N_NODES * N_NODES - NE) * 2) / 4;   // 1101000 float4s
    if (gid >= nfl4) return;
    float c0 = c2[0], c1 = c2[1];
    float4 q = make_float4(c0, c1, c0, c1);
    ((float4*)(out + NE * 2))[gid] = q;
}

// ---------------- edge-pair MLP + softmax for rows [0, E) -------------------
__global__ void k_edge_mlp(const int* __restrict__ src, const int* __restrict__ dst,
                           const float* __restrict__ x2,
                           const float* __restrict__ fc1w, const float* __restrict__ fc1b,
                           const float* __restrict__ fc2w, const float* __restrict__ fc2b,
                           float* __restrict__ out) {
    __shared__ float w1s[64 * 32];
    __shared__ float b1s[32];
    __shared__ float w2s[64];
    __shared__ float b2s[2];
    int t = threadIdx.x;
    for (int idx = t; idx < 64 * 32; idx += 256) w1s[idx] = fc1w[idx];
    if (t < 32) b1s[t] = fc1b[t];
    if (t < 64) w2s[t] = fc2w[t];
    if (t < 2)  b2s[t] = fc2b[t];
    __syncthreads();
    int e = blockIdx.x * 256 + t;
    if (e >= NE) return;
    int si = src[e], di = dst[e];
    float v[64];
    #pragma unroll
    for (int k = 0; k < 32; ++k) v[k] = x2[si * 32 + k];
    #pragma unroll
    for (int k = 0; k < 32; ++k) v[32 + k] = x2[di * 32 + k];
    float l0 = b2s[0], l1 = b2s[1];
    #pragma unroll 4
    for (int j = 0; j < 32; ++j) {
        float a = b1s[j];
        #pragma unroll
        for (int k = 0; k < 64; ++k) a = fmaf(v[k], w1s[k * 32 + j], a);
        a = fmaxf(a, 0.f);
        l0 = fmaf(a, w2s[2 * j], l0);
        l1 = fmaf(a, w2s[2 * j + 1], l1);
    }
    float mx = fmaxf(l0, l1);
    float e0 = __expf(l0 - mx), e1 = __expf(l1 - mx);
    float inv = 1.f / (e0 + e1);
    out[2 * e]     = e0 * inv;
    out[2 * e + 1] = e1 * inv;
}

extern "C" void kernel_launch(void* const* d_in, const int* in_sizes, int n_in,
                              void* d_out, int out_size, void* d_ws, size_t ws_size,
                              hipStream_t stream) {
    (void)in_sizes; (void)n_in; (void)out_size; (void)ws_size;
    const float* x    = (const float*)d_in[0];
    const int*  edges = (const int*)d_in[1];
    const float* ef   = (const float*)d_in[2];
    const float* W1   = (const float*)d_in[3];
    const float* as1  = (const float*)d_in[4];
    const float* ad1  = (const float*)d_in[5];
    const float* We   = (const float*)d_in[6];
    const float* ate  = (const float*)d_in[7];
    const float* b1   = (const float*)d_in[8];
    const float* W2   = (const float*)d_in[9];
    const float* as2  = (const float*)d_in[10];
    const float* ad2  = (const float*)d_in[11];
    const float* b2   = (const float*)d_in[12];
    const float* fc1w = (const float*)d_in[13];
    const float* fc1b = (const float*)d_in[14];
    const float* fc2w = (const float*)d_in[15];
    const float* fc2b = (const float*)d_in[16];
    const int* src = edges;
    const int* dst = edges + NE;
    float* out = (float*)d_out;

    // workspace carve-up (256B aligned chunks), ~3.5 MB total
    char* w = (char*)d_ws;
    auto alloc = [&](size_t bytes) -> char* {
        char* p = w;
        w += (bytes + 255) & ~(size_t)255;
        return p;
    };
    float* h1      = (float*)alloc((size_t)N_NODES * HC * 4);
    float* asrc1   = (float*)alloc((size_t)N_NODES * HEADS * 4);
    float* adst1   = (float*)alloc((size_t)N_NODES * HEADS * 4);
    float* extra   = (float*)alloc((size_t)ETOT * HEADS * 4);
    float* sumattr = (float*)alloc((size_t)N_NODES * EDIM * 4);
    int*   deg     = (int*)  alloc((size_t)N_NODES * 4);
    int*   off     = (int*)  alloc((size_t)(N_NODES + 1) * 4);
    int*   fillc   = (int*)  alloc((size_t)N_NODES * 4);
    int*   csr_src = (int*)  alloc((size_t)ETOT * 4);
    int*   csr_eid = (int*)  alloc((size_t)ETOT * 4);
    float* x1      = (float*)alloc((size_t)N_NODES * OUT_DIM * 4);
    float* h2      = (float*)alloc((size_t)N_NODES * HC * 4);
    float* asrc2   = (float*)alloc((size_t)N_NODES * HEADS * 4);
    float* adst2   = (float*)alloc((size_t)N_NODES * HEADS * 4);
    float* x2      = (float*)alloc((size_t)N_NODES * OUT_DIM * 4);
    float* c2      = (float*)alloc(16);

    const int B = 256;
    k_init<<<(N_NODES * EDIM + B - 1) / B, B, 0, stream>>>(deg, fillc, sumattr);
    k_deg_attr<<<(NE * EDIM + B - 1) / B, B, 0, stream>>>(dst, ef, deg, sumattr);
    k_scan<<<1, 512, 0, stream>>>(deg, off);
    k_scatter<<<(ETOT + B - 1) / B, B, 0, stream>>>(src, dst, off, fillc, csr_src, csr_eid);
    k_extra<<<(ETOT * HEADS + B - 1) / B, B, 0, stream>>>(ef, We, ate, sumattr, deg, extra);
    k_proj<IN_DIM><<<N_NODES, HC, 0, stream>>>(x, W1, as1, ad1, h1, asrc1, adst1);
    k_gat<<<N_NODES, HC, 0, stream>>>(h1, asrc1, adst1, extra, off, csr_src, csr_eid, b1, x1);
    k_proj<OUT_DIM><<<N_NODES, HC, 0, stream>>>(x1, W2, as2, ad2, h2, asrc2, adst2);
    k_gat<<<N_NODES, HC, 0, stream>>>(h2, asrc2, adst2, nullptr, off, csr_src, csr_eid, b2, x2);
    k_const<<<1, 64, 0, stream>>>(fc1b, fc2w, fc2b, c2);
    const int nfl4 = ((N_NODES * N_NODES - NE) * 2) / 4;
    k_fill<<<(nfl4 + B - 1) / B, B, 0, stream>>>(c2, out);
    k_edge_mlp<<<(NE + B - 1) / B, B, 0, stream>>>(src, dst, x2, fc1w, fc1b, fc2w, fc2b, out);
}

// Round 2
// 157.877 us; speedup vs baseline: 1.2750x; 1.2750x over previous
//
#include <hip/hip_runtime.h>
#include <cmath>

#define N_NODES 1500
#define NE 48000
#define ETOT (NE + N_NODES)   // 49500
#define IN_DIM 128
#define OUT_DIM 32
#define HEADS 4
#define HC 128                // HEADS*OUT
#define EDIM 16
#define CH 128                // gat edge-chunk per block iteration

// ---------------- init: zero accumulators (ws is poisoned 0xAA each call) ---
__global__ void k_init(int* deg, int* fillc, float* sumattr) {
    int gid = blockIdx.x * blockDim.x + threadIdx.x;
    if (gid < N_NODES) { deg[gid] = 0; fillc[gid] = 0; }
    if (gid < N_NODES * EDIM) sumattr[gid] = 0.f;
}

// ---------------- degree + incoming-edge-attr sums (for self-loop 'mean') ---
__global__ void k_deg_attr(const int* __restrict__ dst, const float* __restrict__ ef,
                           int* deg, float* sumattr) {
    int gid = blockIdx.x * blockDim.x + threadIdx.x;
    if (gid >= NE * EDIM) return;
    int e = gid >> 4, k = gid & 15;
    int d = dst[e];
    atomicAdd(&sumattr[d * EDIM + k], ef[gid]);
    if (k == 0) atomicAdd(&deg[d], 1);
}

// ---------------- exclusive scan of (deg+1) -> CSR offsets, single block ----
__global__ void k_scan(const int* __restrict__ deg, int* __restrict__ off) {
    __shared__ int part[512];
    int t = threadIdx.x;
    int base = t * 3;
    int d0 = (base     < N_NODES) ? deg[base] + 1     : 0;
    int d1 = (base + 1 < N_NODES) ? deg[base + 1] + 1 : 0;
    int d2 = (base + 2 < N_NODES) ? deg[base + 2] + 1 : 0;
    int sum = d0 + d1 + d2;
    part[t] = sum;
    __syncthreads();
    for (int o = 1; o < 512; o <<= 1) {
        int v = (t >= o) ? part[t - o] : 0;
        __syncthreads();
        part[t] += v;
        __syncthreads();
    }
    int excl = part[t] - sum;
    if (base     <= N_NODES) off[base]     = excl;
    if (base + 1 <= N_NODES) off[base + 1] = excl + d0;
    if (base + 2 <= N_NODES) off[base + 2] = excl + d0 + d1;
}

// ---------------- scatter edges (incl. self-loops) into CSR by dst ----------
__global__ void k_scatter(const int* __restrict__ src, const int* __restrict__ dst,
                          const int* __restrict__ off, int* fillc,
                          int* __restrict__ csr_src, int* __restrict__ csr_eid) {
    int e = blockIdx.x * blockDim.x + threadIdx.x;
    if (e >= ETOT) return;
    int s, d;
    if (e < NE) { s = src[e]; d = dst[e]; } else { s = d = e - NE; }
    int pos = atomicAdd(&fillc[d], 1);
    int idx = off[d] + pos;
    csr_src[idx] = s;
    csr_eid[idx] = e;
}

// ---------------- extra[e,h] = ea[e,:] @ P[:,h],  P = We contracted w/ att_e
__global__ void k_extra(const float* __restrict__ ef, const float* __restrict__ We,
                        const float* __restrict__ att_e, const float* __restrict__ sumattr,
                        const int* __restrict__ deg, float* __restrict__ extra) {
    __shared__ float P[EDIM * HEADS];
    int t = threadIdx.x;
    if (t < EDIM * HEADS) {
        int k = t >> 2, hh = t & 3;
        float a = 0.f;
        #pragma unroll
        for (int c = 0; c < OUT_DIM; ++c)
            a = fmaf(We[k * HC + hh * OUT_DIM + c], att_e[hh * OUT_DIM + c], a);
        P[t] = a;   // P[k*4+hh]
    }
    __syncthreads();
    int gid = blockIdx.x * blockDim.x + t;
    if (gid >= ETOT * HEADS) return;
    int e = gid >> 2, hh = gid & 3;
    float a = 0.f;
    if (e < NE) {
        #pragma unroll
        for (int k = 0; k < EDIM; ++k) a = fmaf(ef[e * EDIM + k], P[k * 4 + hh], a);
    } else {
        int i = e - NE;
        float inv = 1.0f / fmaxf((float)deg[i], 1.0f);
        #pragma unroll
        for (int k = 0; k < EDIM; ++k) a = fmaf(sumattr[i * EDIM + k] * inv, P[k * 4 + hh], a);
    }
    extra[gid] = a;
}

// ---------------- h1 = x @ W1, 4 nodes per block (amortize W reads) ---------
__global__ void k_proj1(const float* __restrict__ xin, const float* __restrict__ W,
                        const float* __restrict__ a_src, const float* __restrict__ a_dst,
                        float* __restrict__ h, float* __restrict__ asrc, float* __restrict__ adst) {
    __shared__ float xs[4][IN_DIM];
    int i0 = blockIdx.x * 4, t = threadIdx.x;
    #pragma unroll
    for (int r = 0; r < 4; ++r) xs[r][t] = xin[(i0 + r) * IN_DIM + t];
    __syncthreads();
    float acc0 = 0.f, acc1 = 0.f, acc2 = 0.f, acc3 = 0.f;
    for (int k = 0; k < IN_DIM; ++k) {
        float w = W[k * HC + t];
        acc0 = fmaf(xs[0][k], w, acc0);
        acc1 = fmaf(xs[1][k], w, acc1);
        acc2 = fmaf(xs[2][k], w, acc2);
        acc3 = fmaf(xs[3][k], w, acc3);
    }
    float as = a_src[t], ad = a_dst[t];
    int hh = t >> 5, c = t & 31;
    float accs[4] = {acc0, acc1, acc2, acc3};
    #pragma unroll
    for (int r = 0; r < 4; ++r) {
        h[(i0 + r) * HC + t] = accs[r];
        float ps = accs[r] * as, pd = accs[r] * ad;
        #pragma unroll
        for (int o = 16; o >= 1; o >>= 1) {
            ps += __shfl_down(ps, o, 32);
            pd += __shfl_down(pd, o, 32);
        }
        if (c == 0) { asrc[(i0 + r) * 4 + hh] = ps; adst[(i0 + r) * 4 + hh] = pd; }
    }
}

// ---------------- GAT aggregate, phase-split (parallel gathers, no serial
//                  dependent-load chain). MODE 1: +extra, fused proj2 epilogue.
//                  MODE 2: fused u/v (edge-MLP layer-1 factorization) epilogue.
template <int MODE>
__global__ void k_gat(const float* __restrict__ h, const float* __restrict__ asrc,
                      const float* __restrict__ adst, const float* __restrict__ extra,
                      const int* __restrict__ off, const int* __restrict__ csr_src,
                      const int* __restrict__ csr_eid, const float* __restrict__ bias,
                      const float* __restrict__ Wn, const float* __restrict__ a_s2,
                      const float* __restrict__ a_d2,
                      float* __restrict__ h2, float* __restrict__ asrc2,
                      float* __restrict__ adst2, float* __restrict__ uv) {
    __shared__ int   sns[CH];
    __shared__ float sal[CH * HEADS];
    __shared__ float red[HC];
    __shared__ float xrow[OUT_DIM];
    int i = blockIdx.x, t = threadIdx.x;
    int hh = t >> 5, c = t & 31;
    float4 ad4 = *(const float4*)&adst[i * 4];
    int beg = off[i], end = off[i + 1];
    float m = -INFINITY, s = 0.f, acc = 0.f;
    for (int pos = beg; pos < end; pos += CH) {
        int cnt = min(CH, end - pos);
        __syncthreads();            // protect sns/sal vs previous chunk's readers
        if (t < cnt) {
            int j = pos + t;
            int sn = csr_src[j];
            sns[t] = sn;
            float4 a4 = *(const float4*)&asrc[sn * 4];
            float ax = a4.x + ad4.x, ay = a4.y + ad4.y, az = a4.z + ad4.z, aw = a4.w + ad4.w;
            if (MODE == 1) {
                float4 e4 = *(const float4*)&extra[csr_eid[j] * 4];
                ax += e4.x; ay += e4.y; az += e4.z; aw += e4.w;
            }
            ax = ax > 0.f ? ax : 0.2f * ax;
            ay = ay > 0.f ? ay : 0.2f * ay;
            az = az > 0.f ? az : 0.2f * az;
            aw = aw > 0.f ? aw : 0.2f * aw;
            *(float4*)&sal[t * 4] = make_float4(ax, ay, az, aw);
        }
        __syncthreads();
        // per-head chunk max (32 lanes of this head)
        float cm = -INFINITY;
        for (int q = c; q < cnt; q += 32) cm = fmaxf(cm, sal[q * 4 + hh]);
        #pragma unroll
        for (int o = 16; o >= 1; o >>= 1) cm = fmaxf(cm, __shfl_down(cm, o, 32));
        cm = __shfl(cm, 0, 32);
        float mn = fmaxf(m, cm);
        float r = __expf(m - mn);   // exp(-inf)=0 on first chunk
        float cs = 0.f;
        for (int q = c; q < cnt; q += 32) {
            float w = __expf(sal[q * 4 + hh] - mn);
            sal[q * 4 + hh] = w;    // same 32-lane subgroup reads below: intra-wave
            cs += w;
        }
        #pragma unroll
        for (int o = 16; o >= 1; o >>= 1) cs += __shfl_down(cs, o, 32);
        cs = __shfl(cs, 0, 32);
        s = s * r + cs;
        acc *= r;
        m = mn;
        // weighted feature sum: coalesced h rows, no dependent gathers
        for (int jj = 0; jj < cnt; ++jj)
            acc = fmaf(sal[jj * 4 + hh], h[sns[jj] * HC + t], acc);
    }
    red[t] = acc / s;               // self loop -> s > 0
    __syncthreads();
    if (t < OUT_DIM)
        xrow[t] = 0.25f * (red[t] + red[t + 32] + red[t + 64] + red[t + 96]) + bias[t];
    __syncthreads();
    if (MODE == 1) {
        // fused proj2: h2 = x1 @ W2 + attention dots
        float a2 = 0.f;
        #pragma unroll
        for (int k = 0; k < OUT_DIM; ++k) a2 = fmaf(xrow[k], Wn[k * HC + t], a2);
        h2[i * HC + t] = a2;
        float ps = a2 * a_s2[t], pd = a2 * a_d2[t];
        #pragma unroll
        for (int o = 16; o >= 1; o >>= 1) {
            ps += __shfl_down(ps, o, 32);
            pd += __shfl_down(pd, o, 32);
        }
        if (c == 0) { asrc2[i * 4 + hh] = ps; adst2[i * 4 + hh] = pd; }
    } else {
        // fused edge-MLP layer-1 factorization:
        // u[i,j] = x2[i]@fc1w[0:32,j], v[i,j] = x2[i]@fc1w[32:64,j]
        if (t < 64) {
            int j = t & 31, ro = (t >> 5) * 32;
            float a2 = 0.f;
            #pragma unroll
            for (int k = 0; k < OUT_DIM; ++k) a2 = fmaf(xrow[k], Wn[(ro + k) * 32 + j], a2);
            uv[i * 64 + t] = a2;
        }
    }
}

// ---------------- broadcast-fill rows [E, n*n): constant computed inline ----
__global__ void k_fill(const float* __restrict__ fc1b, const float* __restrict__ fc2w,
                       const float* __restrict__ fc2b, float* __restrict__ out) {
    float l0 = fc2b[0], l1 = fc2b[1];
    #pragma unroll
    for (int j = 0; j < 32; ++j) {
        float a = fmaxf(fc1b[j], 0.f);
        l0 = fmaf(a, fc2w[2 * j], l0);
        l1 = fmaf(a, fc2w[2 * j + 1], l1);
    }
    float mx = fmaxf(l0, l1);
    float e0 = __expf(l0 - mx), e1 = __expf(l1 - mx);
    float inv = 1.f / (e0 + e1);
    float4 q = make_float4(e0 * inv, e1 * inv, e0 * inv, e1 * inv);
    int gid = blockIdx.x * blockDim.x + threadIdx.x;
    const int nfl4 = ((N_NODES * N_NODES - NE) * 2) / 4;   // 1101000
    if (gid < nfl4) ((float4*)(out + NE * 2))[gid] = q;
}

// ---------------- edge MLP via u/v factorization + softmax ------------------
__global__ void k_edge_mlp(const int* __restrict__ src, const int* __restrict__ dst,
                           const float* __restrict__ uv,
                           const float* __restrict__ fc1b,
                           const float* __restrict__ fc2w, const float* __restrict__ fc2b,
                           float* __restrict__ out) {
    __shared__ float b1s[32], w2s[64], b2s[2];
    int t = threadIdx.x;
    if (t < 32) b1s[t] = fc1b[t];
    if (t < 64) w2s[t] = fc2w[t];
    if (t < 2)  b2s[t] = fc2b[t];
    __syncthreads();
    int e = blockIdx.x * 256 + t;
    if (e >= NE) return;
    int si = src[e], di = dst[e];
    const float4* up = (const float4*)&uv[si * 64];
    const float4* vp = (const float4*)&uv[di * 64 + 32];
    float l0 = b2s[0], l1 = b2s[1];
    #pragma unroll
    for (int q = 0; q < 8; ++q) {
        float4 u4 = up[q], v4 = vp[q];
        float a;
        a = fmaxf(u4.x + v4.x + b1s[4*q+0], 0.f); l0 = fmaf(a, w2s[8*q+0], l0); l1 = fmaf(a, w2s[8*q+1], l1);
        a = fmaxf(u4.y + v4.y + b1s[4*q+1], 0.f); l0 = fmaf(a, w2s[8*q+2], l0); l1 = fmaf(a, w2s[8*q+3], l1);
        a = fmaxf(u4.z + v4.z + b1s[4*q+2], 0.f); l0 = fmaf(a, w2s[8*q+4], l0); l1 = fmaf(a, w2s[8*q+5], l1);
        a = fmaxf(u4.w + v4.w + b1s[4*q+3], 0.f); l0 = fmaf(a, w2s[8*q+6], l0); l1 = fmaf(a, w2s[8*q+7], l1);
    }
    float mx = fmaxf(l0, l1);
    float e0 = __expf(l0 - mx), e1 = __expf(l1 - mx);
    float inv = 1.f / (e0 + e1);
    *(float2*)&out[2 * e] = make_float2(e0 * inv, e1 * inv);
}

extern "C" void kernel_launch(void* const* d_in, const int* in_sizes, int n_in,
                              void* d_out, int out_size, void* d_ws, size_t ws_size,
                              hipStream_t stream) {
    (void)in_sizes; (void)n_in; (void)out_size; (void)ws_size;
    const float* x    = (const float*)d_in[0];
    const int*  edges = (const int*)d_in[1];
    const float* ef   = (const float*)d_in[2];
    const float* W1   = (const float*)d_in[3];
    const float* as1  = (const float*)d_in[4];
    const float* ad1  = (const float*)d_in[5];
    const float* We   = (const float*)d_in[6];
    const float* ate  = (const float*)d_in[7];
    const float* b1   = (const float*)d_in[8];
    const float* W2   = (const float*)d_in[9];
    const float* as2  = (const float*)d_in[10];
    const float* ad2  = (const float*)d_in[11];
    const float* b2   = (const float*)d_in[12];
    const float* fc1w = (const float*)d_in[13];
    const float* fc1b = (const float*)d_in[14];
    const float* fc2w = (const float*)d_in[15];
    const float* fc2b = (const float*)d_in[16];
    const int* src = edges;
    const int* dst = edges + NE;
    float* out = (float*)d_out;

    char* w = (char*)d_ws;
    auto alloc = [&](size_t bytes) -> char* {
        char* p = w;
        w += (bytes + 255) & ~(size_t)255;
        return p;
    };
    float* h1      = (float*)alloc((size_t)N_NODES * HC * 4);
    float* asrc1   = (float*)alloc((size_t)N_NODES * HEADS * 4);
    float* adst1   = (float*)alloc((size_t)N_NODES * HEADS * 4);
    float* extra   = (float*)alloc((size_t)ETOT * HEADS * 4);
    float* sumattr = (float*)alloc((size_t)N_NODES * EDIM * 4);
    int*   deg     = (int*)  alloc((size_t)N_NODES * 4);
    int*   off     = (int*)  alloc((size_t)(N_NODES + 1) * 4);
    int*   fillc   = (int*)  alloc((size_t)N_NODES * 4);
    int*   csr_src = (int*)  alloc((size_t)ETOT * 4);
    int*   csr_eid = (int*)  alloc((size_t)ETOT * 4);
    float* h2      = (float*)alloc((size_t)N_NODES * HC * 4);
    float* asrc2   = (float*)alloc((size_t)N_NODES * HEADS * 4);
    float* adst2   = (float*)alloc((size_t)N_NODES * HEADS * 4);
    float* uv      = (float*)alloc((size_t)N_NODES * 64 * 4);

    const int B = 256;
    k_init<<<(N_NODES * EDIM + B - 1) / B, B, 0, stream>>>(deg, fillc, sumattr);
    k_deg_attr<<<(NE * EDIM + B - 1) / B, B, 0, stream>>>(dst, ef, deg, sumattr);
    k_scan<<<1, 512, 0, stream>>>(deg, off);
    k_scatter<<<(ETOT + B - 1) / B, B, 0, stream>>>(src, dst, off, fillc, csr_src, csr_eid);
    k_extra<<<(ETOT * HEADS + B - 1) / B, B, 0, stream>>>(ef, We, ate, sumattr, deg, extra);
    k_proj1<<<N_NODES / 4, HC, 0, stream>>>(x, W1, as1, ad1, h1, asrc1, adst1);
    k_gat<1><<<N_NODES, HC, 0, stream>>>(h1, asrc1, adst1, extra, off, csr_src, csr_eid, b1,
                                         W2, as2, ad2, h2, asrc2, adst2, nullptr);
    k_gat<2><<<N_NODES, HC, 0, stream>>>(h2, asrc2, adst2, nullptr, off, csr_src, csr_eid, b2,
                                         fc1w, nullptr, nullptr, nullptr, nullptr, nullptr, uv);
    k_fill<<<((((N_NODES * N_NODES - NE) * 2) / 4) + B - 1) / B, B, 0, stream>>>(fc1b, fc2w, fc2b, out);
    k_edge_mlp<<<(NE + B - 1) / B, B, 0, stream>>>(src, dst, uv, fc1b, fc2w, fc2b, out);
}